// Round 7
// baseline (269.000 us; speedup 1.0000x reference)
//
#include <hip/hip_runtime.h>

// NRI MLP decoder, fused f16-MFMA pipeline, v23.
// B=4, T=64 (t<63 out), A=32, R=992 (=32 recv x 31 edges), D=64, S=4,
// E=4 (type 0 skipped), MH=MO=NH=256.
//
//   h1[b,t,r] = lrelu(PS[send(r)] + PRb[rec(r)])   (PRb has b1 folded, from ka)
//   msg = lrelu(h1 @ W2 + b2) ; agg[a] = sum_{r:rec=a} g[r]*msg[r]
// kb v23: BARRIER-FREE K-loop. Measurement across v18/v20/v22: per-step wall
// time is a fixed ~3300cy serial chain regardless of per-step MFMA count or
// resident blocks — the block-wide barrier forces all pipes to run back-to-
// back (time = SUM of LDS+VALU+MFMA, ~135us; max(pipes) ~55us). Barriers
// existed only for the h1 dbuf + Bt ring handoffs. v23 removes both:
//  - B-panel (N=128 x K=256 = 64KB) fully LDS-resident, staged once in the
//    prologue, then READ-ONLY: no ring, no handoff.
//  - h1 in registers (v22's exact wave=1-atom mapping, af[2], acc[2][4]):
//    each wave builds its own A-frags (dup x2). P loads for step s+1 issue at
//    the top of step s and are consumed after the MFMA cluster (~250cy gap
//    covers L1/L2 latency) — fixing v21's same-step exposure.
//  - K-loop has ZERO barriers / waitcnt asm; 16 independent waves/CU free-run
//    so one wave's ds_reads overlap another's MFMAs.
// sched_barrier(0) fences pin per-step load issue (stop the unroller from
// hoisting all 8 steps' P loads -> spill). Regs ~60V + 32 AGPR << (512,4)
// cap. LDS 65KB -> 2 blocks/CU. Math identical to v22 (passed).

typedef _Float16 f16x8 __attribute__((ext_vector_type(8)));
typedef float f32x4 __attribute__((ext_vector_type(4)));

#define MFMAH(a, b, c) __builtin_amdgcn_mfma_f32_16x16x32_f16((a), (b), (c), 0, 0, 0)

// full-drain barrier (__syncthreads semantics, explicit) — prologue only
#define KBAR0() do {                                             \
  __builtin_amdgcn_sched_barrier(0);                             \
  asm volatile("s_waitcnt vmcnt(0) lgkmcnt(0)" ::: "memory");    \
  __builtin_amdgcn_s_barrier();                                  \
  __builtin_amdgcn_sched_barrier(0);                             \
} while (0)

__device__ __forceinline__ unsigned pkh(float lo, float hi) {
  auto h = __builtin_amdgcn_cvt_pkrtz(lo, hi);
  return __builtin_bit_cast(unsigned, h);
}
__device__ __forceinline__ unsigned short f2h(float f) {
  return __builtin_bit_cast(unsigned short, (_Float16)f);
}
__device__ __forceinline__ float lrelu(float x) { return x > 0.f ? x : 0.01f * x; }

__device__ __forceinline__ void gl16(const void* g, void* l) {
  __builtin_amdgcn_global_load_lds(
      (const __attribute__((address_space(1))) unsigned int*)(unsigned long long)g,
      (__attribute__((address_space(3))) unsigned int*)(unsigned int)(unsigned long long)l,
      16, 0, 0);
}

// ---------------- kernel W: weight transpose + f16 convert ----------------
// W2F fragment-linear: [e][kstep 0..7][ntile 0..15][lane 0..63][j 0..7]
//   n = ntile*16 + (lane&15), k = kstep*32 + (lane>>4)*8 + j.
__global__ __launch_bounds__(256) void kw(
    const float* __restrict__ w1, const float* __restrict__ w2,
    const float* __restrict__ o1, const float* __restrict__ o2, const float* __restrict__ o3,
    unsigned short* __restrict__ W1T, unsigned short* __restrict__ W2F,
    unsigned short* __restrict__ O1T, unsigned short* __restrict__ O2T,
    unsigned short* __restrict__ O3T) {
  int i = blockIdx.x * 256 + threadIdx.x;
  if (i < 98304) {
    int k = i & 63, n = (i >> 6) & 255, eh = i >> 14;
    int e = (eh >> 1) + 1, half = eh & 1;
    W1T[i] = f2h(w1[(e * 128 + half * 64 + k) * 256 + n]);
    return;
  }
  i -= 98304;
  if (i < 196608) {
    int j = i & 7, l = (i >> 3) & 63, t = (i >> 9) & 15, s = (i >> 13) & 7, e = i >> 16;
    int n = t * 16 + (l & 15);
    int k = s * 32 + (l >> 4) * 8 + j;
    W2F[i] = f2h(w2[(e + 1) * 65536 + k * 256 + n]);
    return;
  }
  i -= 196608;
  if (i < 81920) {
    int k = i % 320, n = i / 320;
    O1T[i] = f2h(o1[k * 256 + n]);
    return;
  }
  i -= 81920;
  if (i < 65536) {
    int k = i & 255, n = i >> 8;
    O2T[i] = f2h(o2[k * 256 + n]);
    return;
  }
  i -= 65536;
  {
    int k = i & 255, n = i >> 8;
    O3T[i] = f2h(o3[k * 64 + n]);
  }
}

// ---------------- kernel A: per-atom projections P + gates G ----------------
__global__ __launch_bounds__(256) void ka(
    const float* __restrict__ inputs, const float* __restrict__ state,
    const float* __restrict__ rel_type, const unsigned short* __restrict__ W1T,
    const float* __restrict__ b1g,
    unsigned short* __restrict__ P, float* __restrict__ G) {
  int t = blockIdx.x, b = blockIdx.y;
  int bt = b * 63 + t;
  int tid = threadIdx.x, lane = tid & 63, wid = tid >> 6;
  int waveM = wid & 1, waveN = wid >> 1;
  __shared__ __align__(16) _Float16 xa[32 * 72];
  __shared__ __align__(16) _Float16 Bt[256 * 72];
  __shared__ __align__(16) _Float16 Ps[32 * 256];
  __shared__ float ss[32][4];
  {
    int a = tid >> 3, d0 = (tid & 7) * 8;
    const float* src = inputs + (((b * 32 + a) * 64 + t) << 6) + d0;
    float4 v0 = *(const float4*)src;
    float4 v1 = *(const float4*)(src + 4);
    uint4 w;
    w.x = pkh(v0.x, v0.y); w.y = pkh(v0.z, v0.w);
    w.z = pkh(v1.x, v1.y); w.w = pkh(v1.z, v1.w);
    *(uint4*)&xa[a * 72 + d0] = w;
  }
  if (tid < 128) {
    int a = tid >> 2, s = tid & 3;
    ss[a][s] = state[((b * 32 + a) * 64 + t) * 4 + s];
  }
  __syncthreads();
  #pragma unroll
  for (int q = 0; q < 12; ++q) {
    int task = tid + q * 256;
    int e = task >> 10, rem = task & 1023, a = rem >> 5, k = rem & 31;
    float g = 0.f;
    if (k < 31) {
      int sA = k + (k >= a ? 1 : 0);
      int r = a * 31 + k;
      const float* rt = rel_type + (b * 992 + r) * 16 + (e + 1);
      g = rt[0] * ss[sA][0] + rt[4] * ss[sA][1] + rt[8] * ss[sA][2] + rt[12] * ss[sA][3];
    }
    G[(bt * 3 + e) * 1024 + a * 32 + k] = g;
  }
  for (int eh = 0; eh < 6; ++eh) {
    #pragma unroll
    for (int q = 0; q < 8; ++q) {
      int cid = tid + q * 256;
      int n = cid >> 3, c8 = (cid & 7) * 8;
      *(uint4*)&Bt[n * 72 + c8] = *(const uint4*)&W1T[(eh * 256 + n) * 64 + c8];
    }
    __syncthreads();
    f32x4 acc[8];
    #pragma unroll
    for (int f = 0; f < 8; ++f) acc[f] = f32x4{0.f, 0.f, 0.f, 0.f};
    #pragma unroll
    for (int ik = 0; ik < 2; ++ik) {
      int k0 = ik * 32;
      f16x8 av = *(const f16x8*)&xa[(waveM * 16 + (lane & 15)) * 72 + k0 + (lane >> 4) * 8];
      #pragma unroll
      for (int f = 0; f < 8; ++f) {
        f16x8 bv = *(const f16x8*)&Bt[(waveN * 128 + f * 16 + (lane & 15)) * 72 + k0 + (lane >> 4) * 8];
        acc[f] = MFMAH(av, bv, acc[f]);
      }
    }
    #pragma unroll
    for (int f = 0; f < 8; ++f) {
      int c = waveN * 128 + f * 16 + (lane & 15);
      float bias = (eh & 1) ? b1g[((eh >> 1) + 1) * 256 + c] : 0.f;
      #pragma unroll
      for (int i = 0; i < 4; ++i) {
        int rrow = waveM * 16 + (lane >> 4) * 4 + i;
        Ps[rrow * 256 + c] = (_Float16)(acc[f][i] + bias);
      }
    }
    __syncthreads();
    unsigned short* dst = P + (bt * 6 + eh) * 8192;
    #pragma unroll
    for (int q = 0; q < 4; ++q) {
      int o = (tid + q * 256) * 8;
      *(uint4*)&dst[o] = *(const uint4*)&Ps[o];
    }
    __syncthreads();
  }
}

// ---------------- kernel B v23: barrier-free loop, resident B-panel ---------
// grid.x = 12096 = 8*1512; swz: (q,nh) fastest, then bt, then e (v22 mapping).
__global__ __launch_bounds__(512, 4) void kb(
    const unsigned short* __restrict__ P, const float* __restrict__ G,
    const unsigned short* __restrict__ W2F, const float* __restrict__ b2g,
    unsigned short* __restrict__ AGG3) {
  int bx = blockIdx.x;
  int swz = (bx & 7) * 1512 + (bx >> 3);
  int e = swz / 4032;
  int rem = swz - e * 4032;
  int bt = rem >> 4;
  int sub = rem & 15;
  int q = sub >> 1, nh = sub & 1;
  int a0 = q * 4;
  int tid = threadIdx.x, lane = tid & 63, wid = tid >> 6;
  int waveM = wid & 3, waveN = wid >> 2;   // 4M x 2N
  int lane15 = lane & 15, kqh = lane >> 4; // 0..3

  __shared__ __align__(16) _Float16 Bp[32768];  // 64KB: N128 x K256, frag-linear
  __shared__ float gs[128];
  __shared__ float b2s[128];
  // LDS total: 65536 + 512 + 512 = 66560B -> 2 blocks/CU.

  const unsigned short* psrc  = P + (bt * 6 + e * 2) * 8192;  // PS slab (send)
  const unsigned short* prsrc = psrc + 8192;                   // PRb slab
  const unsigned short* w2f   = W2F + e * 65536 + nh * 4096;   // this block's 8 ntiles

  // af addressing: wave owns atom al = a0+waveM; frag f row = f*16+lane15.
  int al = a0 + waveM;
  int bk0 = lane15;                                   // frag 0 edge slot (<=15)
  int bk1 = 16 + lane15;                              // frag 1 edge slot (16..31)
  int bs0 = bk0 + (bk0 >= al ? 1 : 0);
  int bs1 = (bk1 < 31) ? (bk1 + (bk1 >= al ? 1 : 0)) : 0;  // k=31 pad (g=0)
  const unsigned short* pv0g = psrc + bs0 * 256 + kqh * 8;
  const unsigned short* pv1g = psrc + bs1 * 256 + kqh * 8;
  const unsigned short* rvg  = prsrc + al * 256 + kqh * 8;

  // ---- prologue: P(0) loads; stage full B panel; gates/bias; build af(0) ----
  f16x8 pvA = *(const f16x8*)pv0g;
  f16x8 pvB = *(const f16x8*)pv1g;
  f16x8 rv0 = *(const f16x8*)rvg;
  __builtin_amdgcn_sched_barrier(0);
  #pragma unroll
  for (int j = 0; j < 8; ++j) {
    int c = j * 512 + tid;  // chunk id: ks = c>>9, r = c&511
    gl16(w2f + (c >> 9) * 8192 + (c & 511) * 8, (char*)&Bp[0] + c * 16);
  }
  if (tid < 128) gs[tid] = G[((bt * 3 + e) << 10) + a0 * 32 + tid];
  else if (tid < 256) b2s[tid - 128] = b2g[(e + 1) * 256 + nh * 128 + (tid - 128)];
  f16x8 af0, af1;
  {
    f16x8 h = pvA + rv0;
    af0 = __builtin_elementwise_max(h, h * (_Float16)0.01f);
    h = pvB + rv0;
    af1 = __builtin_elementwise_max(h, h * (_Float16)0.01f);
  }
  KBAR0();  // B panel + gs/b2s ready. LAST barrier in the kernel.

  f32x4 acc[2][4];
  #pragma unroll
  for (int f = 0; f < 2; ++f)
    #pragma unroll
    for (int g2 = 0; g2 < 4; ++g2) acc[f][g2] = f32x4{0.f, 0.f, 0.f, 0.f};

  #pragma unroll
  for (int s = 0; s < 8; ++s) {
    // issue P(s+1) loads first — consumed after the MFMA cluster (~250cy gap)
    f16x8 pA, pB, rN;
    if (s < 7) {
      pA = *(const f16x8*)(pv0g + (s + 1) * 32);
      pB = *(const f16x8*)(pv1g + (s + 1) * 32);
      rN = *(const f16x8*)(rvg + (s + 1) * 32);
    }
    __builtin_amdgcn_sched_barrier(0);  // pin per-step issue (no cross-step hoist)
    // bv(s) reads from the resident panel (conflict-free lane-linear)
    f16x8 bv[4];
    #pragma unroll
    for (int g2 = 0; g2 < 4; ++g2)
      bv[g2] = *(const f16x8*)&Bp[s * 4096 + (waveN * 4 + g2) * 512 + lane * 8];
    // MFMA cluster
    __builtin_amdgcn_s_setprio(1);
    #pragma unroll
    for (int g2 = 0; g2 < 4; ++g2) {
      acc[0][g2] = MFMAH(af0, bv[g2], acc[0][g2]);
      acc[1][g2] = MFMAH(af1, bv[g2], acc[1][g2]);
    }
    __builtin_amdgcn_s_setprio(0);
    // build af(s+1) from the loads issued at step top
    if (s < 7) {
      f16x8 h = pA + rN;
      af0 = __builtin_elementwise_max(h, h * (_Float16)0.01f);
      h = pB + rN;
      af1 = __builtin_elementwise_max(h, h * (_Float16)0.01f);
    }
  }

  // epilogue (v22-verified): p(al,c) = sum_k g[k]*lrelu(acc+b2)
  _Float16* aggh = (_Float16*)AGG3;
  #pragma unroll
  for (int g2 = 0; g2 < 4; ++g2) {
    int cl = (waveN * 4 + g2) * 16 + lane15;  // 0..127 within this nh half
    float bb = b2s[cl];
    float p = 0.f;
    #pragma unroll
    for (int f = 0; f < 2; ++f) {
      int k4 = f * 16 + kqh * 4;
      #pragma unroll
      for (int i = 0; i < 4; ++i)
        p += gs[waveM * 32 + k4 + i] * lrelu(acc[f][g2][i] + bb);
    }
    p += __shfl_xor(p, 16, 64);
    p += __shfl_xor(p, 32, 64);
    if (lane < 16)
      aggh[(size_t)e * 2064384 + (((bt * 32 + al) << 8) + nh * 128 + cl)] = (_Float16)p;
  }
}

// ---------------- kernel C: output MLP 320->256->256->64 + residual ----------------
__global__ __launch_bounds__(256) void kc(
    const float* __restrict__ inputs, const unsigned short* __restrict__ AGG3,
    const unsigned short* __restrict__ O1T, const unsigned short* __restrict__ O2T,
    const unsigned short* __restrict__ O3T,
    const float* __restrict__ ob1, const float* __restrict__ ob2, const float* __restrict__ ob3,
    float* __restrict__ out) {
  int t = blockIdx.x, b = blockIdx.y;
  int bt = b * 63 + t;
  int tid = threadIdx.x, lane = tid & 63, wid = tid >> 6;
  int waveM = wid & 1, waveN = wid >> 1;
  __shared__ __align__(16) _Float16 aug[32 * 328];
  __shared__ __align__(16) _Float16 h1[32 * 264];
  __shared__ __align__(16) _Float16 h2[32 * 264];
  __shared__ __align__(16) _Float16 Bt[256 * 40];
  __shared__ __align__(16) float xs[32 * 64];
  __shared__ float lb1[256], lb2[256], lb3[64];
  {
    int a = tid >> 3, d0 = (tid & 7) * 8;
    const float* src = inputs + (((b * 32 + a) * 64 + t) << 6) + d0;
    float4 v0 = *(const float4*)src;
    float4 v1 = *(const float4*)(src + 4);
    *(float4*)&xs[a * 64 + d0] = v0;
    *(float4*)&xs[a * 64 + d0 + 4] = v1;
    uint4 w;
    w.x = pkh(v0.x, v0.y); w.y = pkh(v0.z, v0.w);
    w.z = pkh(v1.x, v1.y); w.w = pkh(v1.z, v1.w);
    *(uint4*)&aug[a * 328 + d0] = w;
  }
  #pragma unroll
  for (int qq = 0; qq < 4; ++qq) {
    int cid = tid + qq * 256;
    int a = cid >> 5, c8 = (cid & 31) * 8;
    size_t o = ((size_t)(bt * 32 + a) << 8) + c8;
    f16x8 v0 = *(const f16x8*)&AGG3[o];
    f16x8 v1 = *(const f16x8*)&AGG3[2064384 + o];
    f16x8 v2 = *(const f16x8*)&AGG3[4128768 + o];
    f16x8 s = v0 + v1 + v2;
    *(uint4*)&aug[a * 328 + 64 + c8] = __builtin_bit_cast(uint4, s);
  }
  lb1[tid] = ob1[tid];
  lb2[tid] = ob2[tid];
  if (tid < 64) lb3[tid] = ob3[tid];
  __syncthreads();
  f32x4 acc[8];
  #pragma unroll
  for (int f = 0; f < 8; ++f) acc[f] = f32x4{0.f, 0.f, 0.f, 0.f};
  for (int kk = 0; kk < 10; ++kk) {  // fc1: K=320
    #pragma unroll
    for (int q = 0; q < 4; ++q) {
      int cid = tid + q * 256;
      int n = cid >> 2, c8 = (cid & 3) * 8;
      *(uint4*)&Bt[n * 40 + c8] = *(const uint4*)&O1T[n * 320 + kk * 32 + c8];
    }
    __syncthreads();
    f16x8 av = *(const f16x8*)&aug[(waveM * 16 + (lane & 15)) * 328 + kk * 32 + (lane >> 4) * 8];
    #pragma unroll
    for (int f = 0; f < 8; ++f) {
      f16x8 bv = *(const f16x8*)&Bt[(waveN * 128 + f * 16 + (lane & 15)) * 40 + (lane >> 4) * 8];
      acc[f] = MFMAH(av, bv, acc[f]);
    }
    __syncthreads();
  }
  #pragma unroll
  for (int f = 0; f < 8; ++f) {
    int c = waveN * 128 + f * 16 + (lane & 15);
    #pragma unroll
    for (int i = 0; i < 4; ++i) {
      int r = waveM * 16 + (lane >> 4) * 4 + i;
      h1[r * 264 + c] = (_Float16)lrelu(acc[f][i] + lb1[c]);
    }
  }
  __syncthreads();
  #pragma unroll
  for (int f = 0; f < 8; ++f) acc[f] = f32x4{0.f, 0.f, 0.f, 0.f};
  for (int kk = 0; kk < 8; ++kk) {  // fc2: K=256
    #pragma unroll
    for (int q = 0; q < 4; ++q) {
      int cid = tid + q * 256;
      int n = cid >> 2, c8 = (cid & 3) * 8;
      *(uint4*)&Bt[n * 40 + c8] = *(const uint4*)&O2T[n * 256 + kk * 32 + c8];
    }
    __syncthreads();
    f16x8 av = *(const f16x8*)&h1[(waveM * 16 + (lane & 15)) * 264 + kk * 32 + (lane >> 4) * 8];
    #pragma unroll
    for (int f = 0; f < 8; ++f) {
      f16x8 bv = *(const f16x8*)&Bt[(waveN * 128 + f * 16 + (lane & 15)) * 40 + (lane >> 4) * 8];
      acc[f] = MFMAH(av, bv, acc[f]);
    }
    __syncthreads();
  }
  #pragma unroll
  for (int f = 0; f < 8; ++f) {
    int c = waveN * 128 + f * 16 + (lane & 15);
    #pragma unroll
    for (int i = 0; i < 4; ++i) {
      int r = waveM * 16 + (lane >> 4) * 4 + i;
      h2[r * 264 + c] = (_Float16)lrelu(acc[f][i] + lb2[c]);
    }
  }
  __syncthreads();
  f32x4 a3[2];
  a3[0] = f32x4{0.f, 0.f, 0.f, 0.f};
  a3[1] = f32x4{0.f, 0.f, 0.f, 0.f};
  for (int kk = 0; kk < 8; ++kk) {  // fc3: K=256, N=64
    {
      int n = tid >> 2, c8 = (tid & 3) * 8;
      *(uint4*)&Bt[n * 40 + c8] = *(const uint4*)&O3T[n * 256 + kk * 32 + c8];
    }
    __syncthreads();
    f16x8 av = *(const f16x8*)&h2[(waveM * 16 + (lane & 15)) * 264 + kk * 32 + (lane >> 4) * 8];
    #pragma unroll
    for (int f = 0; f < 2; ++f) {
      f16x8 bv = *(const f16x8*)&Bt[(waveN * 32 + f * 16 + (lane & 15)) * 40 + (lane >> 4) * 8];
      a3[f] = MFMAH(av, bv, a3[f]);
    }
    __syncthreads();
  }
  #pragma unroll
  for (int f = 0; f < 2; ++f) {
    int d = waveN * 32 + f * 16 + (lane & 15);
    #pragma unroll
    for (int i = 0; i < 4; ++i) {
      int a = waveM * 16 + (lane >> 4) * 4 + i;
      out[((b * 32 + a) * 63 + t) * 64 + d] = a3[f][i] + lb3[d] + xs[a * 64 + d];
    }
  }
}

extern "C" void kernel_launch(void* const* d_in, const int* in_sizes, int n_in,
                              void* d_out, int out_size, void* d_ws, size_t ws_size,
                              hipStream_t stream) {
  const float* inputs   = (const float*)d_in[0];
  const float* state    = (const float*)d_in[1];
  const float* rel_type = (const float*)d_in[2];
  const float* w1  = (const float*)d_in[5];
  const float* b1  = (const float*)d_in[6];
  const float* w2  = (const float*)d_in[7];
  const float* b2  = (const float*)d_in[8];
  const float* o1w = (const float*)d_in[9];
  const float* o1b = (const float*)d_in[10];
  const float* o2w = (const float*)d_in[11];
  const float* o2b = (const float*)d_in[12];
  const float* o3w = (const float*)d_in[13];
  const float* o3b = (const float*)d_in[14];
  char* ws = (char*)d_ws;
  unsigned short* W1T = (unsigned short*)(ws + 0);
  unsigned short* W2F = (unsigned short*)(ws + 196608);     // 393216 B (frag-linear)
  unsigned short* O1T = (unsigned short*)(ws + 589824);
  unsigned short* O2T = (unsigned short*)(ws + 753664);
  unsigned short* O3T = (unsigned short*)(ws + 884736);
  unsigned short* Pp  = (unsigned short*)(ws + 917504);     // 24772608 B
  float* G    = (float*)(ws + 25690112);                    // 3096576 B
  unsigned short* AGG3 = (unsigned short*)(ws + 28786688);  // 12386304 B
  float* out = (float*)d_out;

  kw<<<1792, 256, 0, stream>>>(w1, w2, o1w, o2w, o3w, W1T, W2F, O1T, O2T, O3T);
  ka<<<dim3(63, 4), 256, 0, stream>>>(inputs, state, rel_type, W1T, b1, Pp, G);
  kb<<<12096, 512, 0, stream>>>(Pp, G, W2F, b2, AGG3);
  kc<<<dim3(63, 4), 256, 0, stream>>>(inputs, AGG3, O1T, O2T, O3T, o1b, o2b, o3b, out);
}

// Round 8
// 165.667 us; speedup vs baseline: 1.6237x; 1.6237x over previous
//
#include <hip/hip_runtime.h>

// NRI MLP decoder, fused f16-MFMA pipeline, v25.
// B=4, T=64 (t<63 out), A=32, R=992 (=32 recv x 31 edges), D=64, S=4,
// E=4 (type 0 skipped), MH=MO=NH=256.
//
//   h1[b,t,r] = lrelu(PS[send(r)] + PRb[rec(r)])   (PRb has b1 folded, from ka)
//   msg = lrelu(h1 @ W2 + b2) ; agg[a] = sum_{r:rec=a} g[r]*msg[r]
// kb v25 = v18 (best measured: 3-slot counted-vmcnt Bt ring, conflict-free
// frag-linear layouts, lgkm-only barriers, 2 blocks/CU) + PHASE-BREAKING
// s_sleep. Measurement across v18/v20/v22/v23: per-step wall time is a fixed
// ~3300cy = SUM of pipe times because the CU's two resident blocks run their
// {LDS burst -> MFMA burst -> VALU} phases IN PHASE (simultaneous launch,
// identical phase lengths -> stable lockstep; both queue on LDS together,
// then both on MFMA). Anti-phase (A's LDS under B's MFMA) gives step ~= max
// of pipes (~2100cy) and is also self-sustaining once entered. v25 enters it:
// the initial slot-1 blocks (bx in [256,512) = the second resident block on
// every CU under linear/XCD-interleaved dispatch) sleep ~1700cy (half a step)
// right after the prologue barrier. Subsequent generations inherit the offset
// (each finishing block spawns its successor at its own phase). Cost if the
// hypothesis is wrong: 512 x 1728cy of one-time idle ~= 0.7us. Everything
// else is byte-identical to v18.

typedef _Float16 f16x8 __attribute__((ext_vector_type(8)));
typedef float f32x4 __attribute__((ext_vector_type(4)));

#define MFMAH(a, b, c) __builtin_amdgcn_mfma_f32_16x16x32_f16((a), (b), (c), 0, 0, 0)

// full-drain barrier (__syncthreads semantics, explicit) — prologue only
#define KBAR0() do {                                             \
  __builtin_amdgcn_sched_barrier(0);                             \
  asm volatile("s_waitcnt vmcnt(0) lgkmcnt(0)" ::: "memory");    \
  __builtin_amdgcn_s_barrier();                                  \
  __builtin_amdgcn_sched_barrier(0);                             \
} while (0)

// LDS-only barrier: drains ds ops, leaves global loads in flight
#define KBARL() do {                                             \
  __builtin_amdgcn_sched_barrier(0);                             \
  asm volatile("s_waitcnt lgkmcnt(0)" ::: "memory");             \
  __builtin_amdgcn_s_barrier();                                  \
  __builtin_amdgcn_sched_barrier(0);                             \
} while (0)

__device__ __forceinline__ unsigned pkh(float lo, float hi) {
  auto h = __builtin_amdgcn_cvt_pkrtz(lo, hi);
  return __builtin_bit_cast(unsigned, h);
}
__device__ __forceinline__ unsigned short f2h(float f) {
  return __builtin_bit_cast(unsigned short, (_Float16)f);
}
__device__ __forceinline__ float lrelu(float x) { return x > 0.f ? x : 0.01f * x; }

__device__ __forceinline__ void gl16(const void* g, void* l) {
  __builtin_amdgcn_global_load_lds(
      (const __attribute__((address_space(1))) unsigned int*)(unsigned long long)g,
      (__attribute__((address_space(3))) unsigned int*)(unsigned int)(unsigned long long)l,
      16, 0, 0);
}

// ---------------- kernel W: weight transpose + f16 convert ----------------
// W2F fragment-linear: [e][kstep 0..7][ntile 0..15][lane 0..63][j 0..7]
//   n = ntile*16 + (lane&15), k = kstep*32 + (lane>>4)*8 + j.
__global__ __launch_bounds__(256) void kw(
    const float* __restrict__ w1, const float* __restrict__ w2,
    const float* __restrict__ o1, const float* __restrict__ o2, const float* __restrict__ o3,
    unsigned short* __restrict__ W1T, unsigned short* __restrict__ W2F,
    unsigned short* __restrict__ O1T, unsigned short* __restrict__ O2T,
    unsigned short* __restrict__ O3T) {
  int i = blockIdx.x * 256 + threadIdx.x;
  if (i < 98304) {
    int k = i & 63, n = (i >> 6) & 255, eh = i >> 14;
    int e = (eh >> 1) + 1, half = eh & 1;
    W1T[i] = f2h(w1[(e * 128 + half * 64 + k) * 256 + n]);
    return;
  }
  i -= 98304;
  if (i < 196608) {
    int j = i & 7, l = (i >> 3) & 63, t = (i >> 9) & 15, s = (i >> 13) & 7, e = i >> 16;
    int n = t * 16 + (l & 15);
    int k = s * 32 + (l >> 4) * 8 + j;
    W2F[i] = f2h(w2[(e + 1) * 65536 + k * 256 + n]);
    return;
  }
  i -= 196608;
  if (i < 81920) {
    int k = i % 320, n = i / 320;
    O1T[i] = f2h(o1[k * 256 + n]);
    return;
  }
  i -= 81920;
  if (i < 65536) {
    int k = i & 255, n = i >> 8;
    O2T[i] = f2h(o2[k * 256 + n]);
    return;
  }
  i -= 65536;
  {
    int k = i & 255, n = i >> 8;
    O3T[i] = f2h(o3[k * 64 + n]);
  }
}

// ---------------- kernel A: per-atom projections P + gates G ----------------
__global__ __launch_bounds__(256) void ka(
    const float* __restrict__ inputs, const float* __restrict__ state,
    const float* __restrict__ rel_type, const unsigned short* __restrict__ W1T,
    const float* __restrict__ b1g,
    unsigned short* __restrict__ P, float* __restrict__ G) {
  int t = blockIdx.x, b = blockIdx.y;
  int bt = b * 63 + t;
  int tid = threadIdx.x, lane = tid & 63, wid = tid >> 6;
  int waveM = wid & 1, waveN = wid >> 1;
  __shared__ __align__(16) _Float16 xa[32 * 72];
  __shared__ __align__(16) _Float16 Bt[256 * 72];
  __shared__ __align__(16) _Float16 Ps[32 * 256];
  __shared__ float ss[32][4];
  {
    int a = tid >> 3, d0 = (tid & 7) * 8;
    const float* src = inputs + (((b * 32 + a) * 64 + t) << 6) + d0;
    float4 v0 = *(const float4*)src;
    float4 v1 = *(const float4*)(src + 4);
    uint4 w;
    w.x = pkh(v0.x, v0.y); w.y = pkh(v0.z, v0.w);
    w.z = pkh(v1.x, v1.y); w.w = pkh(v1.z, v1.w);
    *(uint4*)&xa[a * 72 + d0] = w;
  }
  if (tid < 128) {
    int a = tid >> 2, s = tid & 3;
    ss[a][s] = state[((b * 32 + a) * 64 + t) * 4 + s];
  }
  __syncthreads();
  #pragma unroll
  for (int q = 0; q < 12; ++q) {
    int task = tid + q * 256;
    int e = task >> 10, rem = task & 1023, a = rem >> 5, k = rem & 31;
    float g = 0.f;
    if (k < 31) {
      int sA = k + (k >= a ? 1 : 0);
      int r = a * 31 + k;
      const float* rt = rel_type + (b * 992 + r) * 16 + (e + 1);
      g = rt[0] * ss[sA][0] + rt[4] * ss[sA][1] + rt[8] * ss[sA][2] + rt[12] * ss[sA][3];
    }
    G[(bt * 3 + e) * 1024 + a * 32 + k] = g;
  }
  for (int eh = 0; eh < 6; ++eh) {
    #pragma unroll
    for (int q = 0; q < 8; ++q) {
      int cid = tid + q * 256;
      int n = cid >> 3, c8 = (cid & 7) * 8;
      *(uint4*)&Bt[n * 72 + c8] = *(const uint4*)&W1T[(eh * 256 + n) * 64 + c8];
    }
    __syncthreads();
    f32x4 acc[8];
    #pragma unroll
    for (int f = 0; f < 8; ++f) acc[f] = f32x4{0.f, 0.f, 0.f, 0.f};
    #pragma unroll
    for (int ik = 0; ik < 2; ++ik) {
      int k0 = ik * 32;
      f16x8 av = *(const f16x8*)&xa[(waveM * 16 + (lane & 15)) * 72 + k0 + (lane >> 4) * 8];
      #pragma unroll
      for (int f = 0; f < 8; ++f) {
        f16x8 bv = *(const f16x8*)&Bt[(waveN * 128 + f * 16 + (lane & 15)) * 72 + k0 + (lane >> 4) * 8];
        acc[f] = MFMAH(av, bv, acc[f]);
      }
    }
    #pragma unroll
    for (int f = 0; f < 8; ++f) {
      int c = waveN * 128 + f * 16 + (lane & 15);
      float bias = (eh & 1) ? b1g[((eh >> 1) + 1) * 256 + c] : 0.f;
      #pragma unroll
      for (int i = 0; i < 4; ++i) {
        int rrow = waveM * 16 + (lane >> 4) * 4 + i;
        Ps[rrow * 256 + c] = (_Float16)(acc[f][i] + bias);
      }
    }
    __syncthreads();
    unsigned short* dst = P + (bt * 6 + eh) * 8192;
    #pragma unroll
    for (int q = 0; q < 4; ++q) {
      int o = (tid + q * 256) * 8;
      *(uint4*)&dst[o] = *(const uint4*)&Ps[o];
    }
    __syncthreads();
  }
}

// ---------------- kernel B v25: v18 + phase-breaking sleep ------------------
// grid.x = 6048 = 8*756; swz: q fastest, then bt, then e (v8 mapping).
__global__ __launch_bounds__(512, 4) void kb(
    const unsigned short* __restrict__ P, const float* __restrict__ G,
    const unsigned short* __restrict__ W2F, const float* __restrict__ b2g,
    unsigned short* __restrict__ AGG3) {
  int bx = blockIdx.x;
  int swz = (bx & 7) * 756 + (bx >> 3);
  int e = swz / 2016;
  int rem = swz - e * 2016;
  int bt = rem >> 3, q = rem & 7;
  int a0 = q * 4;
  int tid = threadIdx.x, lane = tid & 63, wid = tid >> 6;
  int waveM = wid & 1, waveN = wid >> 1;   // 2M x 4N
  int lane15 = lane & 15, kqh = lane >> 4; // 0..3

  __shared__ __align__(16) _Float16 h1F[2][4096];  // frag-linear dbuf, 16KB
  __shared__ __align__(16) _Float16 Bt[3][8192];   // frag-linear 3-slot ring, 48KB
  __shared__ float gs[128];
  __shared__ float b2s[256];
  // LDS total: 16384 + 49152 + 512 + 1024 = 67072B -> 2 blocks/CU.

  const unsigned short* psrc  = P + (bt * 6 + e * 2) * 8192;  // PS slab (send)
  const unsigned short* prsrc = psrc + 8192;                   // PRb slab
  const unsigned short* w2f   = W2F + e * 65536;               // [step][ntile][lane][8]

  // h1 build mapping: wave w builds tile w, lane-linear write (0 conflicts).
  // lane l -> row w*16+(l&15), k-chunk (l>>4)*8.
  int rrow = wid * 16 + lane15;
  int al0 = rrow >> 5, bk = rrow & 31;   // atom-in-item, edge slot
  int bs = (bk < 31) ? bk + (bk >= a0 + al0 ? 1 : 0) : 0;  // k=31 pad (g=0)
  const unsigned short* pvg = psrc + bs * 256 + kqh * 8;
  const unsigned short* rvg = prsrc + (a0 + al0) * 256 + kqh * 8;
  int h1off = wid * 512 + lane * 8;

  // ---- prologue: stage Bt slots 0,1; gates/bias; build h1(0) ----
  {
    f16x8 pv = *(const f16x8*)(pvg);
    f16x8 rv = *(const f16x8*)(rvg);
    __builtin_amdgcn_sched_barrier(0);   // pv/rv issue before the gl16s
    #pragma unroll
    for (int j = 0; j < 2; ++j) {
      int c = j * 512 + tid;
      gl16(w2f + c * 8, (char*)&Bt[0][0] + c * 16);
      gl16(w2f + 8192 + c * 8, (char*)&Bt[1][0] + c * 16);
    }
    if (tid < 128) gs[tid] = G[((bt * 3 + e) << 10) + a0 * 32 + tid];
    if (tid >= 256) b2s[tid - 256] = b2g[(e + 1) * 256 + (tid - 256)];
    f16x8 h = pv + rv;
    *(f16x8*)&h1F[0][h1off] = __builtin_elementwise_max(h, h * (_Float16)0.01f);
  }
  KBAR0();  // Bt[0],Bt[1] + h1(0) + gs/b2s ready (full drain, once)

  // Phase-breaking offset: the initial slot-1 fill (second resident block on
  // each CU under linear/XCD-interleaved dispatch) sleeps ~half a K-step
  // (~1700cy) so the CU's two blocks run their LDS/MFMA bursts anti-phase.
  // Later generations inherit the offset from their predecessor's finish time.
  if (bx >= 256 && bx < 512) {
    asm volatile("s_sleep 27");
    __builtin_amdgcn_s_barrier();  // re-align the block's own waves
  }

  f32x4 acc[4][4];
  #pragma unroll
  for (int f = 0; f < 4; ++f)
    #pragma unroll
    for (int g2 = 0; g2 < 4; ++g2) acc[f][g2] = f32x4{0.f, 0.f, 0.f, 0.f};

  #pragma unroll
  for (int s = 0; s < 8; ++s) {
    const int buf = s & 1;
    // issue next h1 P loads FIRST (so the compiler's wait before the ds_write
    // counts the 2 newer gl16s -> vmcnt(2), never a full drain)
    f16x8 pv, rv;
    if (s < 7) {
      pv = *(const f16x8*)(pvg + (s + 1) * 32);
      rv = *(const f16x8*)(rvg + (s + 1) * 32);
    }
    __builtin_amdgcn_sched_barrier(0);
    // stage Bt for step s+2 into ring slot (s+2)%3 — consumed two steps later
    if (s < 6) {
      #pragma unroll
      for (int j = 0; j < 2; ++j) {
        int c = j * 512 + tid;
        gl16(w2f + (s + 2) * 8192 + c * 8, (char*)&Bt[(s + 2) % 3][0] + c * 16);
      }
    }
    // MFMA on h1F[buf] x Bt[s%3] — all stride-1 fragment reads
    f16x8 af[4];
    #pragma unroll
    for (int f = 0; f < 4; ++f)
      af[f] = *(const f16x8*)&h1F[buf][(waveM * 4 + f) * 512 + lane * 8];
    __builtin_amdgcn_s_setprio(1);
    #pragma unroll
    for (int g2 = 0; g2 < 4; ++g2) {
      f16x8 bv = *(const f16x8*)&Bt[s % 3][(waveN * 4 + g2) * 512 + lane * 8];
      #pragma unroll
      for (int f = 0; f < 4; ++f)
        acc[f][g2] = MFMAH(af[f], bv, acc[f][g2]);
    }
    __builtin_amdgcn_s_setprio(0);
    if (s < 7) {
      // build h1(s+1): compiler waits vmcnt(2) here (pv/rv needed; 2 gl16 newer)
      f16x8 h = pv + rv;
      *(f16x8*)&h1F[buf ^ 1][h1off] = __builtin_elementwise_max(h, h * (_Float16)0.01f);
      if (s < 6)
        asm volatile("s_waitcnt vmcnt(2)" ::: "memory");  // Bt(s+1) stage done; s+2 in flight
      KBARL();  // lgkm-only: h1 dbuf + Bt slot handoff
    }
  }

  // epilogue: p(al,c) = sum_k g[k]*lrelu(acc+b2); write f16 partial per type
  _Float16* aggh = (_Float16*)AGG3;
  #pragma unroll
  for (int half = 0; half < 2; ++half) {
    int al = waveM * 2 + half;
    #pragma unroll
    for (int g2 = 0; g2 < 4; ++g2) {
      int c = waveN * 64 + g2 * 16 + lane15;
      float bb = b2s[c];
      float p = 0.f;
      #pragma unroll
      for (int fh = 0; fh < 2; ++fh) {
        int f = half * 2 + fh;
        int k4 = fh * 16 + kqh * 4;
        #pragma unroll
        for (int i = 0; i < 4; ++i)
          p += gs[al * 32 + k4 + i] * lrelu(acc[f][g2][i] + bb);
      }
      p += __shfl_xor(p, 16, 64);
      p += __shfl_xor(p, 32, 64);
      if (lane < 16)
        aggh[(size_t)e * 2064384 + (((bt * 32 + a0 + al) << 8) + c)] = (_Float16)p;
    }
  }
}

// ---------------- kernel C: output MLP 320->256->256->64 + residual ----------------
__global__ __launch_bounds__(256) void kc(
    const float* __restrict__ inputs, const unsigned short* __restrict__ AGG3,
    const unsigned short* __restrict__ O1T, const unsigned short* __restrict__ O2T,
    const unsigned short* __restrict__ O3T,
    const float* __restrict__ ob1, const float* __restrict__ ob2, const float* __restrict__ ob3,
    float* __restrict__ out) {
  int t = blockIdx.x, b = blockIdx.y;
  int bt = b * 63 + t;
  int tid = threadIdx.x, lane = tid & 63, wid = tid >> 6;
  int waveM = wid & 1, waveN = wid >> 1;
  __shared__ __align__(16) _Float16 aug[32 * 328];
  __shared__ __align__(16) _Float16 h1[32 * 264];
  __shared__ __align__(16) _Float16 h2[32 * 264];
  __shared__ __align__(16) _Float16 Bt[256 * 40];
  __shared__ __align__(16) float xs[32 * 64];
  __shared__ float lb1[256], lb2[256], lb3[64];
  {
    int a = tid >> 3, d0 = (tid & 7) * 8;
    const float* src = inputs + (((b * 32 + a) * 64 + t) << 6) + d0;
    float4 v0 = *(const float4*)src;
    float4 v1 = *(const float4*)(src + 4);
    *(float4*)&xs[a * 64 + d0] = v0;
    *(float4*)&xs[a * 64 + d0 + 4] = v1;
    uint4 w;
    w.x = pkh(v0.x, v0.y); w.y = pkh(v0.z, v0.w);
    w.z = pkh(v1.x, v1.y); w.w = pkh(v1.z, v1.w);
    *(uint4*)&aug[a * 328 + d0] = w;
  }
  #pragma unroll
  for (int qq = 0; qq < 4; ++qq) {
    int cid = tid + qq * 256;
    int a = cid >> 5, c8 = (cid & 31) * 8;
    size_t o = ((size_t)(bt * 32 + a) << 8) + c8;
    f16x8 v0 = *(const f16x8*)&AGG3[o];
    f16x8 v1 = *(const f16x8*)&AGG3[2064384 + o];
    f16x8 v2 = *(const f16x8*)&AGG3[4128768 + o];
    f16x8 s = v0 + v1 + v2;
    *(uint4*)&aug[a * 328 + 64 + c8] = __builtin_bit_cast(uint4, s);
  }
  lb1[tid] = ob1[tid];
  lb2[tid] = ob2[tid];
  if (tid < 64) lb3[tid] = ob3[tid];
  __syncthreads();
  f32x4 acc[8];
  #pragma unroll
  for (int f = 0; f < 8; ++f) acc[f] = f32x4{0.f, 0.f, 0.f, 0.f};
  for (int kk = 0; kk < 10; ++kk) {  // fc1: K=320
    #pragma unroll
    for (int q = 0; q < 4; ++q) {
      int cid = tid + q * 256;
      int n = cid >> 2, c8 = (cid & 3) * 8;
      *(uint4*)&Bt[n * 40 + c8] = *(const uint4*)&O1T[n * 320 + kk * 32 + c8];
    }
    __syncthreads();
    f16x8 av = *(const f16x8*)&aug[(waveM * 16 + (lane & 15)) * 328 + kk * 32 + (lane >> 4) * 8];
    #pragma unroll
    for (int f = 0; f < 8; ++f) {
      f16x8 bv = *(const f16x8*)&Bt[(waveN * 128 + f * 16 + (lane & 15)) * 40 + (lane >> 4) * 8];
      acc[f] = MFMAH(av, bv, acc[f]);
    }
    __syncthreads();
  }
  #pragma unroll
  for (int f = 0; f < 8; ++f) {
    int c = waveN * 128 + f * 16 + (lane & 15);
    #pragma unroll
    for (int i = 0; i < 4; ++i) {
      int r = waveM * 16 + (lane >> 4) * 4 + i;
      h1[r * 264 + c] = (_Float16)lrelu(acc[f][i] + lb1[c]);
    }
  }
  __syncthreads();
  #pragma unroll
  for (int f = 0; f < 8; ++f) acc[f] = f32x4{0.f, 0.f, 0.f, 0.f};
  for (int kk = 0; kk < 8; ++kk) {  // fc2: K=256
    #pragma unroll
    for (int q = 0; q < 4; ++q) {
      int cid = tid + q * 256;
      int n = cid >> 2, c8 = (cid & 3) * 8;
      *(uint4*)&Bt[n * 40 + c8] = *(const uint4*)&O2T[n * 256 + kk * 32 + c8];
    }
    __syncthreads();
    f16x8 av = *(const f16x8*)&h1[(waveM * 16 + (lane & 15)) * 264 + kk * 32 + (lane >> 4) * 8];
    #pragma unroll
    for (int f = 0; f < 8; ++f) {
      f16x8 bv = *(const f16x8*)&Bt[(waveN * 128 + f * 16 + (lane & 15)) * 40 + (lane >> 4) * 8];
      acc[f] = MFMAH(av, bv, acc[f]);
    }
    __syncthreads();
  }
  #pragma unroll
  for (int f = 0; f < 8; ++f) {
    int c = waveN * 128 + f * 16 + (lane & 15);
    #pragma unroll
    for (int i = 0; i < 4; ++i) {
      int r = waveM * 16 + (lane >> 4) * 4 + i;
      h2[r * 264 + c] = (_Float16)lrelu(acc[f][i] + lb2[c]);
    }
  }
  __syncthreads();
  f32x4 a3[2];
  a3[0] = f32x4{0.f, 0.f, 0.f, 0.f};
  a3[1] = f32x4{0.f, 0.f, 0.f, 0.f};
  for (int kk = 0; kk < 8; ++kk) {  // fc3: K=256, N=64
    {
      int n = tid >> 2, c8 = (tid & 3) * 8;
      *(uint4*)&Bt[n * 40 + c8] = *(const uint4*)&O3T[n * 256 + kk * 32 + c8];
    }
    __syncthreads();
    f16x8 av = *(const f16x8*)&h2[(waveM * 16 + (lane & 15)) * 264 + kk * 32 + (lane >> 4) * 8];
    #pragma unroll
    for (int f = 0; f < 2; ++f) {
      f16x8 bv = *(const f16x8*)&Bt[(waveN * 32 + f * 16 + (lane & 15)) * 40 + (lane >> 4) * 8];
      a3[f] = MFMAH(av, bv, a3[f]);
    }
    __syncthreads();
  }
  #pragma unroll
  for (int f = 0; f < 2; ++f) {
    int d = waveN * 32 + f * 16 + (lane & 15);
    #pragma unroll
    for (int i = 0; i < 4; ++i) {
      int a = waveM * 16 + (lane >> 4) * 4 + i;
      out[((b * 32 + a) * 63 + t) * 64 + d] = a3[f][i] + lb3[d] + xs[a * 64 + d];
    }
  }
}

extern "C" void kernel_launch(void* const* d_in, const int* in_sizes, int n_in,
                              void* d_out, int out_size, void* d_ws, size_t ws_size,
                              hipStream_t stream) {
  const float* inputs   = (const float*)d_in[0];
  const float* state    = (const float*)d_in[1];
  const float* rel_type = (const float*)d_in[2];
  const float* w1  = (const float*)d_in[5];
  const float* b1  = (const float*)d_in[6];
  const float* w2  = (const float*)d_in[7];
  const float* b2  = (const float*)d_in[8];
  const float* o1w = (const float*)d_in[9];
  const float* o1b = (const float*)d_in[10];
  const float* o2w = (const float*)d_in[11];
  const float* o2b = (const float*)d_in[12];
  const float* o3w = (const float*)d_in[13];
  const float* o3b = (const float*)d_in[14];
  char* ws = (char*)d_ws;
  unsigned short* W1T = (unsigned short*)(ws + 0);
  unsigned short* W2F = (unsigned short*)(ws + 196608);     // 393216 B (frag-linear)
  unsigned short* O1T = (unsigned short*)(ws + 589824);
  unsigned short* O2T = (unsigned short*)(ws + 753664);
  unsigned short* O3T = (unsigned short*)(ws + 884736);
  unsigned short* Pp  = (unsigned short*)(ws + 917504);     // 24772608 B
  float* G    = (float*)(ws + 25690112);                    // 3096576 B
  unsigned short* AGG3 = (unsigned short*)(ws + 28786688);  // 12386304 B
  float* out = (float*)d_out;

  kw<<<1792, 256, 0, stream>>>(w1, w2, o1w, o2w, o3w, W1T, W2F, O1T, O2T, O3T);
  ka<<<dim3(63, 4), 256, 0, stream>>>(inputs, state, rel_type, W1T, b1, Pp, G);
  kb<<<6048, 512, 0, stream>>>(Pp, G, W2F, b2, AGG3);
  kc<<<dim3(63, 4), 256, 0, stream>>>(inputs, AGG3, O1T, O2T, O3T, o1b, o2b, o3b, out);
}